// Round 4
// baseline (109.721 us; speedup 1.0000x reference)
//
#include <hip/hip_runtime.h>
#include <hip/hip_bf16.h>

#define D_ 64
#define HW_ 4096
#define K_ 1024
#define NPTS_ 65536
#define QOUT_ 4194304      // B*D*H*W, offset of idx region in d_out
#define DELTA 0.02f        // ambiguity margin >> 2*eps(bf16-split)
#define INF_ 3.4e38f
#define KSPL 4             // K splits (blocks) -> 256 codes per block
#define KPB  256           // codes per block

typedef short bf16x8 __attribute__((ext_vector_type(8)));
typedef float f32x4 __attribute__((ext_vector_type(4)));

__device__ __forceinline__ void gload_lds16(const float* g, float* l) {
    __builtin_amdgcn_global_load_lds((const __attribute__((address_space(1))) void*)g,
                                     (__attribute__((address_space(3))) void*)l, 16, 0, 0);
}
__device__ __forceinline__ void gload_lds4(const float* g, float* l) {
    __builtin_amdgcn_global_load_lds((const __attribute__((address_space(1))) void*)g,
                                     (__attribute__((address_space(3))) void*)l, 4, 0, 0);
}

// ---- pack kernel: cnorm + bf16 hi/lo split of (-2*cb) in MFMA-fragment order ----
// P layout (shorts): [sp(4)][ch(16)][ks(2)][lvl(2)][lane(64)][8]
//   code j = sp*256 + ch*16 + (l&15), dims d = ks*32 + (l>>4)*8 + i
__global__ __launch_bounds__(256) void vq_pack(const float* __restrict__ cb,
                                               float* __restrict__ cnorm,
                                               short* __restrict__ P) {
    const int t = blockIdx.x * 256 + threadIdx.x;   // 0..4095
    const int sp = t >> 10, ch = (t >> 6) & 15, l = t & 63;
    const int j  = sp * KPB + ch * 16 + (l & 15);
    const int dg = l >> 4;
#pragma unroll
    for (int s = 0; s < 2; ++s) {
        const float* src = cb + j * D_ + s * 32 + dg * 8;
        short hb[8], lb[8];
#pragma unroll
        for (int i = 0; i < 8; ++i) {
            const float v = -2.f * src[i];
            __hip_bfloat16 h = __float2bfloat16(v);
            hb[i] = *(const short*)&h;
            const float r = v - __bfloat162float(h);
            __hip_bfloat16 lo = __float2bfloat16(r);
            lb[i] = *(const short*)&lo;
        }
        short* dh = P + ((size_t)sp * 4096 + ((ch * 2 + s) * 2 + 0) * 64 + l) * 8;
        short* dl = P + ((size_t)sp * 4096 + ((ch * 2 + s) * 2 + 1) * 64 + l) * 8;
#pragma unroll
        for (int i = 0; i < 8; ++i) { dh[i] = hb[i]; dl[i] = lb[i]; }
    }
    if (t < K_) {
        const float4* r = (const float4*)(cb + (size_t)t * D_);
        float s0 = 0.f, s1 = 0.f, s2 = 0.f, s3 = 0.f;
#pragma unroll
        for (int i = 0; i < 16; ++i) {
            float4 v = r[i];
            s0 = fmaf(v.x, v.x, s0); s1 = fmaf(v.y, v.y, s1);
            s2 = fmaf(v.z, v.z, s2); s3 = fmaf(v.w, v.w, s3);
        }
        cnorm[t] = (s0 + s1) + (s2 + s3);
    }
}

// ---- main: K-split MFMA GEMM-argmin, codebook tile resident in LDS ----
// Block = (point-group pg, split sp). 8 waves x 32 points, 256 codes.
// Candidates (m1, m2, i1) per point written to rows 3*sp..3*sp+2 of the
// block's own columns in the quantized-output region of d_out.
__global__ __launch_bounds__(512, 4) void vq_main(const float* __restrict__ x,
                                                  const float* __restrict__ cnorm_g,
                                                  const short* __restrict__ P,
                                                  float* __restrict__ out) {
    __shared__ short cbuf[16 * 2 * 2 * 64 * 8];   // 64 KB: resident codebook tile
    __shared__ float cnt[KPB];                    // 1 KB

    const int tid  = threadIdx.x;
    const int lane = tid & 63;
    const int wid  = tid >> 6;
    const int pg   = blockIdx.x >> 2;
    const int sp   = blockIdx.x & 3;
    const int bb   = pg >> 4;
    const int hw0  = (pg & 15) << 8;

    // stage packed codebook tile (64 KB) + cnorm slice, once
    {
        const float* Pf = (const float*)P + (size_t)sp * 16384;
        float* cf = (float*)cbuf;
#pragma unroll
        for (int r = 0; r < 8; ++r)
            gload_lds16(Pf + r * 2048 + wid * 256 + lane * 4, cf + r * 2048 + wid * 256);
        if (wid < 4) gload_lds4(cnorm_g + sp * KPB + wid * 64 + lane, cnt + wid * 64);
    }

    // load + split x fragments (persistent): lane holds point (l&15), dims (l>>4)*8..+7
    bf16x8 ah[2][2], al[2][2];
    {
        const float* xb = x + (size_t)bb * (D_ * HW_) + hw0;
#pragma unroll
        for (int t = 0; t < 2; ++t) {
            const int p_l = wid * 32 + t * 16 + (lane & 15);
#pragma unroll
            for (int s = 0; s < 2; ++s) {
                const int d0 = s * 32 + (lane >> 4) * 8;
#pragma unroll
                for (int i = 0; i < 8; ++i) {
                    const float v = xb[(size_t)(d0 + i) * HW_ + p_l];
                    __hip_bfloat16 h = __float2bfloat16(v);
                    ah[t][s][i] = *(const short*)&h;
                    const float r = v - __bfloat162float(h);
                    __hip_bfloat16 lo = __float2bfloat16(r);
                    al[t][s][i] = *(const short*)&lo;
                }
            }
        }
    }
    asm volatile("s_waitcnt vmcnt(0)" ::: "memory");
    __syncthreads();

    float m1[8], m2[8];
    int   i1[8];
#pragma unroll
    for (int q = 0; q < 8; ++q) { m1[q] = INF_; m2[q] = INF_; i1[q] = 0; }

    const bf16x8* fr = (const bf16x8*)cbuf;
#pragma unroll
    for (int ch = 0; ch < 16; ++ch) {
        const float cn = cnt[ch * 16 + (lane & 15)];
        bf16x8 bh0 = fr[((ch * 2 + 0) * 2 + 0) * 64 + lane];
        bf16x8 bl0 = fr[((ch * 2 + 0) * 2 + 1) * 64 + lane];
        bf16x8 bh1 = fr[((ch * 2 + 1) * 2 + 0) * 64 + lane];
        bf16x8 bl1 = fr[((ch * 2 + 1) * 2 + 1) * 64 + lane];
        f32x4 acc0 = {cn, cn, cn, cn};   // d2 = ||c||^2 + (-2c).x accumulates in-pipe
        f32x4 acc1 = {cn, cn, cn, cn};
        acc0 = __builtin_amdgcn_mfma_f32_16x16x32_bf16(ah[0][0], bh0, acc0, 0, 0, 0);
        acc1 = __builtin_amdgcn_mfma_f32_16x16x32_bf16(ah[1][0], bh0, acc1, 0, 0, 0);
        acc0 = __builtin_amdgcn_mfma_f32_16x16x32_bf16(al[0][0], bh0, acc0, 0, 0, 0);
        acc1 = __builtin_amdgcn_mfma_f32_16x16x32_bf16(al[1][0], bh0, acc1, 0, 0, 0);
        acc0 = __builtin_amdgcn_mfma_f32_16x16x32_bf16(ah[0][0], bl0, acc0, 0, 0, 0);
        acc1 = __builtin_amdgcn_mfma_f32_16x16x32_bf16(ah[1][0], bl0, acc1, 0, 0, 0);
        acc0 = __builtin_amdgcn_mfma_f32_16x16x32_bf16(ah[0][1], bh1, acc0, 0, 0, 0);
        acc1 = __builtin_amdgcn_mfma_f32_16x16x32_bf16(ah[1][1], bh1, acc1, 0, 0, 0);
        acc0 = __builtin_amdgcn_mfma_f32_16x16x32_bf16(al[0][1], bh1, acc0, 0, 0, 0);
        acc1 = __builtin_amdgcn_mfma_f32_16x16x32_bf16(al[1][1], bh1, acc1, 0, 0, 0);
        acc0 = __builtin_amdgcn_mfma_f32_16x16x32_bf16(ah[0][1], bl1, acc0, 0, 0, 0);
        acc1 = __builtin_amdgcn_mfma_f32_16x16x32_bf16(ah[1][1], bl1, acc1, 0, 0, 0);

        const int kc = sp * KPB + ch * 16 + (lane & 15);
#pragma unroll
        for (int t = 0; t < 2; ++t)
#pragma unroll
            for (int r = 0; r < 4; ++r) {
                const int q = t * 4 + r;
                const float d2 = (t == 0) ? acc0[r] : acc1[r];
                if (d2 < m1[q]) { m2[q] = m1[q]; m1[q] = d2; i1[q] = kc; }
                else            { m2[q] = fminf(m2[q], d2); }
            }
    }

    // cross-lane (m1,i1,m2) reduce over the 16 lanes sharing (lane>>4)
#pragma unroll
    for (int q = 0; q < 8; ++q) {
        float a1 = m1[q], a2 = m2[q];
        int   ai = i1[q];
#pragma unroll
        for (int m = 1; m < 16; m <<= 1) {
            const float o1 = __shfl_xor(a1, m);
            const int   oi = __shfl_xor(ai, m);
            const float o2 = __shfl_xor(a2, m);
            const float nm2 = fminf(fminf(a2, o2), fmaxf(a1, o1));
            if (o1 < a1 || (o1 == a1 && oi < ai)) { a1 = o1; ai = oi; }
            a2 = nm2;
        }
        if ((lane & 15) == 0) {
            const int t = q >> 2, r = q & 3;
            const int pt = wid * 32 + t * 16 + 4 * (lane >> 4) + r;
            float* cb_col = out + (size_t)bb * (D_ * HW_) + hw0 + pt;
            cb_col[(size_t)(3 * sp + 0) * HW_] = a1;
            cb_col[(size_t)(3 * sp + 1) * HW_] = a2;
            cb_col[(size_t)(3 * sp + 2) * HW_] = (float)ai;
        }
    }
}

// ---- combine: merge 4 split-candidates, rare exact rescan, gather + write ----
__global__ __launch_bounds__(256) void vq_comb(const float* __restrict__ x,
                                               const float* __restrict__ cb,
                                               const float* __restrict__ cnorm_g,
                                               float* __restrict__ out) {
    __shared__ int res_idx[256];
    __shared__ int flist[256];
    __shared__ int fcnt;

    const int tid  = threadIdx.x;
    const int lane = tid & 63;
    const int wid  = tid >> 6;
    const int pg   = blockIdx.x;
    const int bb   = pg >> 4;
    const int hw0  = (pg & 15) << 8;

    if (tid == 0) fcnt = 0;
    __syncthreads();

    // merge the 4 split candidates (ascending sp keeps np.argmin first-min)
    const float* rdb = out + (size_t)bb * (D_ * HW_) + hw0 + tid;
    float g1 = INF_, g2 = INF_;
    int   gi = 0;
#pragma unroll
    for (int s = 0; s < 4; ++s) {
        const float s1 = rdb[(size_t)(3 * s + 0) * HW_];
        const float s2 = rdb[(size_t)(3 * s + 1) * HW_];
        const int   si = (int)rdb[(size_t)(3 * s + 2) * HW_];
        if (s1 < g1 || (s1 == g1 && si < gi)) { g2 = fminf(g1, s2); g1 = s1; gi = si; }
        else                                  { g2 = fminf(g2, s1); }
    }
    res_idx[tid] = gi;
    if (g2 - g1 <= DELTA) { const int p = atomicAdd(&fcnt, 1); flist[p] = tid; }
    __syncthreads();

    // exact fp32 rescan for ambiguous points (wave-cooperative, 16 codes/lane)
    const int nf = fcnt;
    for (int i = wid; i < nf; i += 4) {
        const int pt = flist[i];
        const float* xr = x + (size_t)bb * (D_ * HW_) + hw0 + pt;
        float acc[16];
#pragma unroll
        for (int c = 0; c < 16; ++c) acc[c] = 0.f;
        for (int d = 0; d < D_; d += 4) {
            const float x0 = xr[(size_t)(d + 0) * HW_];
            const float x1 = xr[(size_t)(d + 1) * HW_];
            const float x2 = xr[(size_t)(d + 2) * HW_];
            const float x3 = xr[(size_t)(d + 3) * HW_];
#pragma unroll
            for (int c = 0; c < 16; ++c) {
                const float4 cf = *(const float4*)(cb + (size_t)(lane * 16 + c) * D_ + d);
                acc[c] = fmaf(x0, cf.x, fmaf(x1, cf.y, fmaf(x2, cf.z, fmaf(x3, cf.w, acc[c]))));
            }
        }
        float b1 = INF_; int bi = 0;
#pragma unroll
        for (int c = 0; c < 16; ++c) {
            const float d2 = fmaf(-2.f, acc[c], cnorm_g[lane * 16 + c]);
            if (d2 < b1) { b1 = d2; bi = lane * 16 + c; }
        }
#pragma unroll
        for (int m = 1; m < 64; m <<= 1) {
            const float o1 = __shfl_xor(b1, m);
            const int   oi = __shfl_xor(bi, m);
            if (o1 < b1 || (o1 == b1 && oi < bi)) { b1 = o1; bi = oi; }
        }
        if (lane == 0) res_idx[pt] = bi;
    }
    __syncthreads();

    // gather winning row + write outputs (overwrites candidate rows 0..11)
    const int bi = res_idx[tid];
    const float4* cw = (const float4*)(cb + (size_t)bi * D_);
    float* op = out + (size_t)bb * (D_ * HW_) + hw0 + tid;
#pragma unroll
    for (int i = 0; i < 16; ++i) {
        const float4 qv = cw[i];
        op[(size_t)(4 * i + 0) * HW_] = qv.x;
        op[(size_t)(4 * i + 1) * HW_] = qv.y;
        op[(size_t)(4 * i + 2) * HW_] = qv.z;
        op[(size_t)(4 * i + 3) * HW_] = qv.w;
    }
    out[(size_t)QOUT_ + (pg << 8) + tid] = (float)bi;
}

extern "C" void kernel_launch(void* const* d_in, const int* in_sizes, int n_in,
                              void* d_out, int out_size, void* d_ws, size_t ws_size,
                              hipStream_t stream) {
    const float* x  = (const float*)d_in[0];   // (16, 64, 64, 64)
    const float* cb = (const float*)d_in[1];   // (1024, 64)
    float* out   = (float*)d_out;
    float* cnorm = (float*)d_ws;                       // 4 KB
    short* P     = (short*)((char*)d_ws + 4096);       // 256 KB packed bf16 codebook

    vq_pack<<<16, 256, 0, stream>>>(cb, cnorm, P);
    vq_main<<<(NPTS_ / 256) * KSPL, 512, 0, stream>>>(x, cnorm, P, out);
    vq_comb<<<NPTS_ / 256, 256, 0, stream>>>(x, cb, cnorm, out);
}